// Round 7
// baseline (1017.344 us; speedup 1.0000x reference)
//
#include <hip/hip_runtime.h>
#include <hip/hip_bf16.h>
#include <stdint.h>

// SingleHeadAttention: B=8 T=2048 E=1024 A=1024, fp32 in/out, bf16 MFMA inside.
// Round 7 = R5 with ONE change: gemm256_core rebuilt at BK=32 with 64 KiB LDS
// so TWO blocks fit per CU (__launch_bounds__(512,4) caps VGPR at 128 for
// 4 waves/SIMD). Cross-block wave overlap covers barrier/latency stalls (m114
// mechanism). 2 barriers per K-tile. score/pv/cvt/transpose = R5 verbatim.

#define BB 8
#define TT 2048
#define EE 1024
#define AA 1024
#define MM (BB * TT)  // 16384

typedef short bf16x8 __attribute__((ext_vector_type(8)));
typedef float f32x4 __attribute__((ext_vector_type(4)));

#define GLOAD_LDS16(g, l)                                                      \
  __builtin_amdgcn_global_load_lds(                                            \
      (const __attribute__((address_space(1))) void*)(g),                      \
      (__attribute__((address_space(3))) void*)(l), 16, 0, 0)

#define SBAR()                               \
  do {                                       \
    __builtin_amdgcn_sched_barrier(0);       \
    __builtin_amdgcn_s_barrier();            \
    __builtin_amdgcn_sched_barrier(0);       \
  } while (0)

#define LGKM(n)                                               \
  do {                                                        \
    asm volatile("s_waitcnt lgkmcnt(" #n ")" ::: "memory");   \
    __builtin_amdgcn_sched_barrier(0);                        \
  } while (0)

#define VMCNT(n)                                              \
  do {                                                        \
    asm volatile("s_waitcnt vmcnt(" #n ")" ::: "memory");     \
    __builtin_amdgcn_sched_barrier(0);                        \
  } while (0)

#define MFMA16(a, b, c) __builtin_amdgcn_mfma_f32_16x16x32_bf16((a), (b), (c), 0, 0, 0)

// ---------------------------------------------------------------------------
// 256x256x(K) bt-GEMM core, BK=32, 8 waves (2M x 4N), per-wave 128x64.
// LDS per operand: [2 buf][256 row][32 kc] shorts = 32 KiB (64 KiB total),
// st_16x32 swizzle (region layout identical to R2's 16KB ksub region).
// Per tile: ph0 {8 ds_read, lgkm, 16 MFMA};
//           ph1 {4 ds_read, lgkm, SBAR, STG A+B(t+2), vmcnt(4), SBAR, 16 MFMA}.
// Hazards: A(t+2)/B(t+2) overwrite tile t's regions only after ph1's first
// SBAR (every wave's a4..7 lgkm-complete; b-reads complete at each wave's ph0
// lgkm which precedes that barrier). t+1's loads drained by vmcnt(4)+SBAR
// before t+1 ph0 reads.
// ---------------------------------------------------------------------------
__device__ __forceinline__ void gemm256_core(
    const short* __restrict__ gA, int lda, int a0row,
    const short* __restrict__ gB, int ldb, int b0row, int NT, short* As,
    short* Bs, f32x4 (*acc)[4]) {
  const int tid = threadIdx.x;
  const int lane = tid & 63;
  const int w = tid >> 6;
  const int wr = w >> 2, wc = w & 3;
  const int lrow = lane & 15;
  const int lk8 = (lane >> 4) * 8;
  const int swz = ((lrow >> 3) & 1) << 4;
  const int baseA = (((wr * 128 + lrow) * 32) + lk8) ^ swz;
  const int baseB = (((wc * 64 + lrow) * 32) + lk8) ^ swz;

  // Staging: 16 KiB region = 16 chunks of 1 KiB; thread covers chunks 2w,2w+1.
  // LDS dest linear; global source pre-swizzled (involution bit9->bit5).
  const short* pA[2];
  const short* pB[2];
  int dL[2];
#pragma unroll
  for (int i = 0; i < 2; ++i) {
    int chunk = 2 * w + i;
    int P = chunk * 1024 + lane * 16;           // phys byte in 16KB region
    int L = P ^ (((P >> 9) & 1) << 5);          // logical byte
    int row = L >> 6;
    int kb2 = (L & 63) >> 1;                    // shorts
    pA[i] = gA + (size_t)(a0row + row) * lda + kb2;
    pB[i] = gB + (size_t)(b0row + row) * ldb + kb2;
    dL[i] = chunk * 512 + lane * 8;
  }

#define STG_A(tl)                                                              \
  do {                                                                         \
    int _o = (tl) * 32;                                                        \
    short* _d = As + (((tl) & 1) << 13);                                       \
    GLOAD_LDS16(pA[0] + _o, _d + dL[0]);                                       \
    GLOAD_LDS16(pA[1] + _o, _d + dL[1]);                                       \
  } while (0)
#define STG_B(tl)                                                              \
  do {                                                                         \
    int _o = (tl) * 32;                                                        \
    short* _d = Bs + (((tl) & 1) << 13);                                       \
    GLOAD_LDS16(pB[0] + _o, _d + dL[0]);                                       \
    GLOAD_LDS16(pB[1] + _o, _d + dL[1]);                                       \
  } while (0)

  // Prologue: stage tiles 0,1 (8 loads/thread); wait tile0; publish.
  STG_A(0); STG_B(0);
  if (NT > 1) {
    STG_A(1); STG_B(1);
    VMCNT(4);
  } else {
    VMCNT(0);
  }
  SBAR();

  for (int t = 0; t < NT; ++t) {
    const short* Ac = As + ((t & 1) << 13);
    const short* Bc = Bs + ((t & 1) << 13);
    bf16x8 a[4], b[4];

    // ---- ph0: read a0..3 + b0..3; MFMA mh0 (no barrier)
#pragma unroll
    for (int m = 0; m < 4; ++m) a[m] = *(const bf16x8*)&Ac[baseA + m * 512];
#pragma unroll
    for (int n = 0; n < 4; ++n) b[n] = *(const bf16x8*)&Bc[baseB + n * 512];
    LGKM(0);
    __builtin_amdgcn_s_setprio(1);
#pragma unroll
    for (int m = 0; m < 4; ++m)
#pragma unroll
      for (int n = 0; n < 4; ++n) acc[m][n] = MFMA16(a[m], b[n], acc[m][n]);
    __builtin_amdgcn_s_setprio(0);

    // ---- ph1: read a4..7; SBAR; stage t+2 over tile t's regions; vmcnt;
    //           SBAR; MFMA mh1 (operands already in regs)
#pragma unroll
    for (int m = 0; m < 4; ++m)
      a[m] = *(const bf16x8*)&Ac[baseA + (m + 4) * 512];
    LGKM(0);
    SBAR();  // all waves' reads of tile t complete
    if (t < NT - 2) {
      STG_A(t + 2);
      STG_B(t + 2);
      VMCNT(4);  // waits tile t+1's 4 loads; leaves t+2's 4 in flight
    } else if (t == NT - 2) {
      VMCNT(0);  // drain tile NT-1's loads
    }
    SBAR();  // tile t+1 buffer published for next ph0
    __builtin_amdgcn_s_setprio(1);
#pragma unroll
    for (int m = 0; m < 4; ++m)
#pragma unroll
      for (int n = 0; n < 4; ++n)
        acc[m + 4][n] = MFMA16(a[m], b[n], acc[m + 4][n]);
    __builtin_amdgcn_s_setprio(0);
  }
#undef STG_A
#undef STG_B
}

// ---------------------------------------------------------------------------
// Fused QKV: grid 768 x 512thr, XCD-chunked (R5 mapping), 2 blocks/CU.
// ---------------------------------------------------------------------------
__global__ __launch_bounds__(512, 4) void qkv_gemm8(
    const short* __restrict__ xb, const short* __restrict__ Wb,
    short* __restrict__ qkv) {
  __shared__ __align__(16) short As[16384];  // 32 KiB
  __shared__ __align__(16) short Bs[16384];  // 32 KiB
  int f = blockIdx.x;
  int s = (f & 7) * 96 + (f >> 3);  // XCD-chunked (768 % 8 == 0)
  int mt = s / 12, nt = s % 12;
  int z = nt >> 2, ntl = nt & 3;
  const short* gB = Wb + (size_t)z * AA * EE + (size_t)(ntl * 256) * EE;
  f32x4 acc[8][4];
#pragma unroll
  for (int m = 0; m < 8; ++m)
#pragma unroll
    for (int n = 0; n < 4; ++n) acc[m][n] = (f32x4){0.f, 0.f, 0.f, 0.f};
  gemm256_core(xb, EE, mt * 256, gB, EE, 0, EE / 32, As, Bs, acc);

  short* o = qkv + (size_t)z * MM * AA;
  int lane = threadIdx.x & 63, w = threadIdx.x >> 6, wr = w >> 2, wc = w & 3;
  int lrow = lane & 15, lk4 = (lane >> 4) * 4;
  int row0 = mt * 256 + wr * 128;
  int col0 = ntl * 256 + wc * 64;
#pragma unroll
  for (int m = 0; m < 8; ++m)
#pragma unroll
    for (int n = 0; n < 4; ++n)
#pragma unroll
      for (int r = 0; r < 4; ++r) {
        int row = row0 + m * 16 + lk4 + r;
        int col = col0 + n * 16 + lrow;
        __hip_bfloat16 h = __float2bfloat16(acc[m][n][r]);
        o[(size_t)row * AA + col] = *(short*)&h;
      }
}

// ---------------------------------------------------------------------------
// R1-style 128x128 helpers (score + pv bodies) — R5 verbatim.
// ---------------------------------------------------------------------------
__device__ __forceinline__ void stage_tile(const short* __restrict__ g,
                                           size_t stride, short* lds, int tid) {
#pragma unroll
  for (int r = 0; r < 4; ++r) {
    int t = r * 256 + tid;
    int row = t >> 3;
    int c = (t & 7) * 8;
    GLOAD_LDS16(g + (size_t)row * stride + c, lds + (size_t)t * 8);
  }
}

__device__ __forceinline__ void mfma_step(const short* As, const short* Bs,
                                          f32x4 acc[4][4], int lane, int wr,
                                          int wc) {
  int lrow = lane & 15;
  int lk = (lane >> 4) * 8;
#pragma unroll
  for (int kk = 0; kk < 64; kk += 32) {
    bf16x8 a[4], b[4];
#pragma unroll
    for (int i = 0; i < 4; ++i)
      a[i] = *(const bf16x8*)&As[(wr * 64 + i * 16 + lrow) * 64 + kk + lk];
#pragma unroll
    for (int j = 0; j < 4; ++j)
      b[j] = *(const bf16x8*)&Bs[(wc * 64 + j * 16 + lrow) * 64 + kk + lk];
#pragma unroll
    for (int i = 0; i < 4; ++i)
#pragma unroll
      for (int j = 0; j < 4; ++j)
        acc[i][j] =
            __builtin_amdgcn_mfma_f32_16x16x32_bf16(a[i], b[j], acc[i][j], 0, 0, 0);
  }
}

__global__ void cvt_bf16(const float* __restrict__ src, short* __restrict__ dst,
                         int n4) {
  int stride = gridDim.x * blockDim.x;
  for (int i = blockIdx.x * blockDim.x + threadIdx.x; i < n4; i += stride) {
    float4 v = ((const float4*)src)[i];
    __hip_bfloat16 h0 = __float2bfloat16(v.x);
    __hip_bfloat16 h1 = __float2bfloat16(v.y);
    __hip_bfloat16 h2 = __float2bfloat16(v.z);
    __hip_bfloat16 h3 = __float2bfloat16(v.w);
    short4 o;
    o.x = *(short*)&h0;
    o.y = *(short*)&h1;
    o.z = *(short*)&h2;
    o.w = *(short*)&h3;
    ((short4*)dst)[i] = o;
  }
}

__global__ void cvt_w3(const float* __restrict__ wq, const float* __restrict__ wk,
                       const float* __restrict__ wv, short* __restrict__ dst) {
  const int n4 = AA * EE / 4;
  int stride = gridDim.x * blockDim.x;
  for (int i = blockIdx.x * blockDim.x + threadIdx.x; i < 3 * n4; i += stride) {
    const float* src = (i < n4) ? wq : (i < 2 * n4 ? wk : wv);
    int ii = (i < n4) ? i : (i < 2 * n4 ? i - n4 : i - 2 * n4);
    float4 v = ((const float4*)src)[ii];
    __hip_bfloat16 h0 = __float2bfloat16(v.x);
    __hip_bfloat16 h1 = __float2bfloat16(v.y);
    __hip_bfloat16 h2 = __float2bfloat16(v.z);
    __hip_bfloat16 h3 = __float2bfloat16(v.w);
    short4 o;
    o.x = *(short*)&h0;
    o.y = *(short*)&h1;
    o.z = *(short*)&h2;
    o.w = *(short*)&h3;
    ((short4*)dst)[i] = o;
  }
}

__global__ __launch_bounds__(256) void transpose_v(const short* __restrict__ Vb,
                                                   short* __restrict__ Vt) {
  __shared__ __align__(16) short lds[64 * 72];
  int t0 = blockIdx.x * 64;
  int d0 = blockIdx.y * 64;
  int b = blockIdx.z;
  int tid = threadIdx.x;
  const short* src = Vb + ((size_t)b * TT + t0) * AA + d0;
#pragma unroll
  for (int r = 0; r < 2; ++r) {
    int t = r * 256 + tid;
    int row = t >> 3;
    int c = (t & 7) * 8;
    *(bf16x8*)&lds[row * 72 + c] = *(const bf16x8*)&src[(size_t)row * AA + c];
  }
  __syncthreads();
  short* dst = Vt + ((size_t)b * AA + d0) * TT + t0;
#pragma unroll
  for (int r = 0; r < 2; ++r) {
    int t = r * 256 + tid;
    int d = t >> 3;
    int c = (t & 7) * 8;
    bf16x8 wv;
#pragma unroll
    for (int e = 0; e < 8; ++e) wv[e] = lds[(c + e) * 72 + d];
    *(bf16x8*)&dst[(size_t)d * TT + c] = wv;
  }
}

// ---------------------------------------------------------------------------
// Scores: compact lower-triangle grid 1088 (8 b x 136 tri), XCD = batch.
// ---------------------------------------------------------------------------
__global__ __launch_bounds__(256) void score_gemm(const short* __restrict__ Qb,
                                                  const short* __restrict__ Kb,
                                                  short* __restrict__ Pu,
                                                  float* __restrict__ lsum) {
  int f = blockIdx.x;
  int b = f & 7;
  int j = f >> 3;  // tri index in [0,136)
  int mt = 0;
  while ((mt + 1) * (mt + 2) / 2 <= j) ++mt;
  int nt = j - mt * (mt + 1) / 2;
  int q0 = mt * 128, c0 = nt * 128;

  __shared__ __align__(16) short As[128 * 64];
  __shared__ __align__(16) short Bs[128 * 64];
  int tid = threadIdx.x;
  int lane = tid & 63, wid = tid >> 6, wr = wid >> 1, wc = wid & 1;
  const short* Q = Qb + (size_t)b * TT * AA;
  const short* K = Kb + (size_t)b * TT * AA;
  f32x4 acc[4][4];
#pragma unroll
  for (int i = 0; i < 4; ++i)
#pragma unroll
    for (int jj = 0; jj < 4; ++jj) acc[i][jj] = (f32x4){0.f, 0.f, 0.f, 0.f};

  for (int k0 = 0; k0 < AA; k0 += 64) {
    stage_tile(Q + (size_t)q0 * AA + k0, AA, As, tid);
    stage_tile(K + (size_t)c0 * AA + k0, AA, Bs, tid);
    __syncthreads();
    mfma_step(As, Bs, acc, lane, wr, wc);
    __syncthreads();
  }
  const float scale = 0.03125f;  // 1/sqrt(1024)
  short* P = Pu + (size_t)b * TT * TT;
  int lrow = lane & 15, lk4 = (lane >> 4) * 4;
#pragma unroll
  for (int i = 0; i < 4; ++i) {
#pragma unroll
    for (int r = 0; r < 4; ++r) {
      int q = q0 + wr * 64 + i * 16 + lk4 + r;
      float rs = 0.f;
#pragma unroll
      for (int jj = 0; jj < 4; ++jj) {
        int kx = c0 + wc * 64 + jj * 16 + lrow;
        float e = (kx <= q) ? __expf(acc[i][jj][r] * scale) : 0.f;
        rs += e;
        __hip_bfloat16 h = __float2bfloat16(e);
        P[(size_t)q * TT + kx] = *(short*)&h;
      }
      rs += __shfl_xor(rs, 1);
      rs += __shfl_xor(rs, 2);
      rs += __shfl_xor(rs, 4);
      rs += __shfl_xor(rs, 8);
      if (lrow == 0) atomicAdd(&lsum[b * TT + q], rs);
    }
  }
}

// ---------------------------------------------------------------------------
// PV balanced pairing: block handles q-strips mt=p and 15-p. grid 512.
// ---------------------------------------------------------------------------
__global__ __launch_bounds__(256) void pv_gemm(const short* __restrict__ Pu,
                                               const short* __restrict__ Vt,
                                               const float* __restrict__ lsum,
                                               float* __restrict__ out) {
  int f = blockIdx.x;
  int b = f & 7;
  int j = f >> 3;          // [0,64)
  int p = j >> 3;          // [0,8)
  int nt = j & 7;
  int n0 = nt * 128;

  __shared__ __align__(16) short As[128 * 64];
  __shared__ __align__(16) short Bs[128 * 64];
  int tid = threadIdx.x;
  int lane = tid & 63, wid = tid >> 6, wr = wid >> 1, wc = wid & 1;
  const short* P = Pu + (size_t)b * TT * TT;
  const short* V = Vt + (size_t)b * AA * TT;
  int lrow = lane & 15, lk4 = (lane >> 4) * 4;

#pragma unroll
  for (int s = 0; s < 2; ++s) {
    int mt = s ? (15 - p) : p;
    int q0 = mt * 128;
    f32x4 acc[4][4];
#pragma unroll
    for (int i = 0; i < 4; ++i)
#pragma unroll
      for (int jj = 0; jj < 4; ++jj) acc[i][jj] = (f32x4){0.f, 0.f, 0.f, 0.f};

    int kend = q0 + 128;
    for (int k0 = 0; k0 < kend; k0 += 64) {
      stage_tile(P + (size_t)q0 * TT + k0, TT, As, tid);
      stage_tile(V + (size_t)n0 * TT + k0, TT, Bs, tid);
      __syncthreads();
      mfma_step(As, Bs, acc, lane, wr, wc);
      __syncthreads();
    }
#pragma unroll
    for (int i = 0; i < 4; ++i) {
#pragma unroll
      for (int r = 0; r < 4; ++r) {
        int q = q0 + wr * 64 + i * 16 + lk4 + r;
        float linv = 1.0f / lsum[b * TT + q];
#pragma unroll
        for (int jj = 0; jj < 4; ++jj) {
          int d = n0 + wc * 64 + jj * 16 + lrow;
          out[((size_t)(b * TT + q)) * AA + d] = acc[i][jj][r] * linv;
        }
      }
    }
  }
}

extern "C" void kernel_launch(void* const* d_in, const int* in_sizes, int n_in,
                              void* d_out, int out_size, void* d_ws,
                              size_t ws_size, hipStream_t stream) {
  const float* x = (const float*)d_in[0];
  const float* Wq = (const float*)d_in[1];
  const float* Wk = (const float*)d_in[2];
  const float* Wv = (const float*)d_in[3];

  char* ws = (char*)d_ws;
  size_t oWb = 0;
  size_t oQb = oWb + (size_t)3 * AA * EE * 2;   // 6 MB weights
  size_t oKb = oQb + (size_t)MM * AA * 2;
  size_t oVb = oKb + (size_t)MM * AA * 2;
  size_t oVt = oVb + (size_t)MM * AA * 2;
  size_t oLs = oVt + (size_t)MM * AA * 2;
  size_t oXb = oLs + (size_t)MM * 4;
  size_t oPu = oXb;  // Pu (67MB) overlaps Xb (33MB): Xb dead after qkv

  short* Wb = (short*)(ws + oWb);
  short* Qb = (short*)(ws + oQb);
  short* Kb = (short*)(ws + oKb);
  short* Vb = (short*)(ws + oVb);
  short* Vt = (short*)(ws + oVt);
  float* Ls = (float*)(ws + oLs);
  short* Xb = (short*)(ws + oXb);
  short* Pu = (short*)(ws + oPu);

  cvt_bf16<<<2048, 256, 0, stream>>>(x, Xb, MM * EE / 4);
  cvt_w3<<<768, 256, 0, stream>>>(Wq, Wk, Wv, Wb);
  hipMemsetAsync(Ls, 0, (size_t)MM * 4, stream);

  qkv_gemm8<<<768, 512, 0, stream>>>(Xb, Wb, Qb);
  transpose_v<<<dim3(32, 16, 8), 256, 0, stream>>>(Vb, Vt);
  score_gemm<<<1088, 256, 0, stream>>>(Qb, Kb, Pu, Ls);
  pv_gemm<<<512, 256, 0, stream>>>(Pu, Vt, Ls, (float*)d_out);
}

// Round 8
// 265.706 us; speedup vs baseline: 3.8288x; 3.8288x over previous
//
#include <hip/hip_runtime.h>
#include <hip/hip_bf16.h>
#include <stdint.h>

// SingleHeadAttention: B=8 T=2048 E=1024 A=1024, fp32 in/out, bf16 MFMA inside.
// Round 8 = R5 (293.7us) + two kernel eliminations:
//   1) V-transpose fused into qkv epilogue (z==2): acc -> 128KB LDS (transposed,
//      granule-XOR swizzle) -> coalesced Vt stores. transpose_v kernel deleted.
//   2) Ls zeroing folded into cvt_w3. memset launch deleted.
// qkv core / score / pv are R5 verbatim.

#define BB 8
#define TT 2048
#define EE 1024
#define AA 1024
#define MM (BB * TT)  // 16384

typedef short bf16x8 __attribute__((ext_vector_type(8)));
typedef float f32x4 __attribute__((ext_vector_type(4)));

#define GLOAD_LDS16(g, l)                                                      \
  __builtin_amdgcn_global_load_lds(                                            \
      (const __attribute__((address_space(1))) void*)(g),                      \
      (__attribute__((address_space(3))) void*)(l), 16, 0, 0)

#define SBAR()                               \
  do {                                       \
    __builtin_amdgcn_sched_barrier(0);       \
    __builtin_amdgcn_s_barrier();            \
    __builtin_amdgcn_sched_barrier(0);       \
  } while (0)

#define LGKM0()                                          \
  do {                                                   \
    asm volatile("s_waitcnt lgkmcnt(0)" ::: "memory");   \
    __builtin_amdgcn_sched_barrier(0);                   \
  } while (0)

#define VMCNT(n)                                              \
  do {                                                        \
    asm volatile("s_waitcnt vmcnt(" #n ")" ::: "memory");     \
    __builtin_amdgcn_sched_barrier(0);                        \
  } while (0)

// ---------------------------------------------------------------------------
// R2/R5 256x256x(K) bt-GEMM core (measured 787 TF in qkv). 512 thr = 8 waves
// (2M x 4N), BK=64. LDS/operand: [2 buf][2 ksub][256 row][32 kc] shorts,
// st_16x32 swizzle. Staging: gload_lds w16, linear dest, pre-swizzled source.
// ---------------------------------------------------------------------------
__device__ __forceinline__ void gemm256_core(
    const short* __restrict__ gA, int lda, int a0row,
    const short* __restrict__ gB, int ldb, int b0row, int NT, short* As,
    short* Bs, f32x4 (*acc)[4]) {
  const int tid = threadIdx.x;
  const int lane = tid & 63;
  const int w = tid >> 6;
  const int wr = w >> 2, wc = w & 3;
  const int lrow = lane & 15;
  const int lk8 = (lane >> 4) * 8;
  const int swz = ((lrow >> 3) & 1) << 4;
  const int baseA = (((wr * 128 + lrow) * 32) + lk8) ^ swz;
  const int baseB = (((wc * 64 + lrow) * 32) + lk8) ^ swz;

  const short* pA[2];
  const short* pB[2];
#pragma unroll
  for (int i = 0; i < 2; ++i) {
    int chunk = 2 * w + i;
    int P = chunk * 1024 + lane * 16;           // phys byte in 16KB region
    int L = P ^ (((P >> 9) & 1) << 5);          // logical byte
    int row = L >> 6;
    int kb2 = (L & 63) >> 1;                    // shorts
    pA[i] = gA + (size_t)(a0row + row) * lda + kb2;
    pB[i] = gB + (size_t)(b0row + row) * ldb + kb2;
  }

  // Prologue: stage tiles 0,1 fully (16 loads/thread), wait tile0 (vmcnt 8).
#pragma unroll
  for (int tl = 0; tl < 2; ++tl) {
    short* Ac = As + tl * 16384;
    short* Bc = Bs + tl * 16384;
#pragma unroll
    for (int s = 0; s < 2; ++s) {
      int off = tl * 64 + s * 32;
      GLOAD_LDS16(pA[0] + off, Ac + s * 8192 + (2 * w) * 512 + lane * 8);
      GLOAD_LDS16(pA[1] + off, Ac + s * 8192 + (2 * w + 1) * 512 + lane * 8);
      GLOAD_LDS16(pB[0] + off, Bc + s * 8192 + (2 * w) * 512 + lane * 8);
      GLOAD_LDS16(pB[1] + off, Bc + s * 8192 + (2 * w + 1) * 512 + lane * 8);
    }
  }
  VMCNT(8);
  SBAR();

  for (int t = 0; t < NT; ++t) {
    short* Ac = As + (t & 1) * 16384;
    short* Bc = Bs + (t & 1) * 16384;
    const bool stg = (t < NT - 2);
    const int off2 = (t + 2) * 64;
    bf16x8 a0[4], a1[4], a2[4], a3[4], b0[4], b1[4];

    // ---- phase 0: read A m0-3/kk0 + B kk0; MFMA (mh0,kk0)
#pragma unroll
    for (int m = 0; m < 4; ++m) a0[m] = *(const bf16x8*)&Ac[baseA + m * 512];
#pragma unroll
    for (int n = 0; n < 4; ++n) b0[n] = *(const bf16x8*)&Bc[baseB + n * 512];
    SBAR();
    LGKM0();
    __builtin_amdgcn_s_setprio(1);
#pragma unroll
    for (int m = 0; m < 4; ++m)
#pragma unroll
      for (int n = 0; n < 4; ++n)
        acc[m][n] = __builtin_amdgcn_mfma_f32_16x16x32_bf16(a0[m], b0[n],
                                                            acc[m][n], 0, 0, 0);
    __builtin_amdgcn_s_setprio(0);
    SBAR();

    // ---- phase 1: read A m4-7/kk0 + A m0-3/kk1; stage B ksub0 (t+2)
#pragma unroll
    for (int m = 0; m < 4; ++m)
      a1[m] = *(const bf16x8*)&Ac[baseA + (m + 4) * 512];
#pragma unroll
    for (int m = 0; m < 4; ++m)
      a2[m] = *(const bf16x8*)&Ac[8192 + baseA + m * 512];
    if (stg) {
      GLOAD_LDS16(pB[0] + off2, Bc + (2 * w) * 512 + lane * 8);
      GLOAD_LDS16(pB[1] + off2, Bc + (2 * w + 1) * 512 + lane * 8);
    }
    SBAR();
    LGKM0();
    __builtin_amdgcn_s_setprio(1);
#pragma unroll
    for (int m = 0; m < 4; ++m)
#pragma unroll
      for (int n = 0; n < 4; ++n)
        acc[m + 4][n] = __builtin_amdgcn_mfma_f32_16x16x32_bf16(
            a1[m], b0[n], acc[m + 4][n], 0, 0, 0);
    __builtin_amdgcn_s_setprio(0);
    SBAR();

    // ---- phase 2: read A m4-7/kk1 + B kk1; stage A ksub0 (t+2)
#pragma unroll
    for (int m = 0; m < 4; ++m)
      a3[m] = *(const bf16x8*)&Ac[8192 + baseA + (m + 4) * 512];
#pragma unroll
    for (int n = 0; n < 4; ++n)
      b1[n] = *(const bf16x8*)&Bc[8192 + baseB + n * 512];
    if (stg) {
      GLOAD_LDS16(pA[0] + off2, Ac + (2 * w) * 512 + lane * 8);
      GLOAD_LDS16(pA[1] + off2, Ac + (2 * w + 1) * 512 + lane * 8);
    }
    SBAR();
    LGKM0();
    __builtin_amdgcn_s_setprio(1);
#pragma unroll
    for (int m = 0; m < 4; ++m)
#pragma unroll
      for (int n = 0; n < 4; ++n)
        acc[m][n] = __builtin_amdgcn_mfma_f32_16x16x32_bf16(a2[m], b1[n],
                                                            acc[m][n], 0, 0, 0);
    __builtin_amdgcn_s_setprio(0);
    SBAR();

    // ---- phase 3: stage A ksub1 + B ksub1 (t+2); boundary vmcnt; MFMA
    if (stg) {
      GLOAD_LDS16(pA[0] + off2 + 32, Ac + 8192 + (2 * w) * 512 + lane * 8);
      GLOAD_LDS16(pA[1] + off2 + 32, Ac + 8192 + (2 * w + 1) * 512 + lane * 8);
      GLOAD_LDS16(pB[0] + off2 + 32, Bc + 8192 + (2 * w) * 512 + lane * 8);
      GLOAD_LDS16(pB[1] + off2 + 32, Bc + 8192 + (2 * w + 1) * 512 + lane * 8);
    }
    if (t < NT - 1) {
      if (stg) {
        VMCNT(8);
      } else {
        VMCNT(0);
      }
    }
    SBAR();
    __builtin_amdgcn_s_setprio(1);
#pragma unroll
    for (int m = 0; m < 4; ++m)
#pragma unroll
      for (int n = 0; n < 4; ++n)
        acc[m + 4][n] = __builtin_amdgcn_mfma_f32_16x16x32_bf16(
            a3[m], b1[n], acc[m + 4][n], 0, 0, 0);
    __builtin_amdgcn_s_setprio(0);
    SBAR();
  }
}

// ---------------------------------------------------------------------------
// Fused QKV: grid 768 x 512thr, XCD-chunked. z<2 -> row-major Q/K store.
// z==2 -> transpose V through the (now dead) 128KB LDS and store Vt[b][d][t].
// ---------------------------------------------------------------------------
__global__ __launch_bounds__(512, 2) void qkv_gemm8(
    const short* __restrict__ xb, const short* __restrict__ Wb,
    short* __restrict__ qk, short* __restrict__ Vt) {
  __shared__ __align__(16) short SH[65536];  // 128 KiB: As | Bs
  short* As = SH;
  short* Bs = SH + 32768;
  int f = blockIdx.x;
  int s = (f & 7) * 96 + (f >> 3);  // XCD-chunked (768 % 8 == 0)
  int mt = s / 12, nt = s % 12;
  int z = nt >> 2, ntl = nt & 3;
  const short* gB = Wb + (size_t)z * AA * EE + (size_t)(ntl * 256) * EE;
  f32x4 acc[8][4];
#pragma unroll
  for (int m = 0; m < 8; ++m)
#pragma unroll
    for (int n = 0; n < 4; ++n) acc[m][n] = (f32x4){0.f, 0.f, 0.f, 0.f};
  gemm256_core(xb, EE, mt * 256, gB, EE, 0, EE / 64, As, Bs, acc);

  int tid = threadIdx.x;
  int lane = tid & 63, w = tid >> 6, wr = w >> 2, wc = w & 3;
  int lrow = lane & 15, lk4 = (lane >> 4) * 4;

  if (z < 2) {
    short* o = qk + (size_t)z * MM * AA;
    int row0 = mt * 256 + wr * 128;
    int col0 = ntl * 256 + wc * 64;
#pragma unroll
    for (int m = 0; m < 8; ++m)
#pragma unroll
      for (int n = 0; n < 4; ++n)
#pragma unroll
        for (int r = 0; r < 4; ++r) {
          int row = row0 + m * 16 + lk4 + r;
          int col = col0 + n * 16 + lrow;
          __hip_bfloat16 h = __float2bfloat16(acc[m][n][r]);
          o[(size_t)row * AA + col] = *(short*)&h;
        }
  } else {
    // V tile: local (lr = t-in-tile, lc = d-in-tile). Stage transposed into
    // SH[lc][lr] bf16 with 8-short-granule XOR swizzle (b128-readable).
    __syncthreads();  // core's final SBAR already drained reads; belt+braces
    int lr0 = wr * 128, lc0 = wc * 64;
#pragma unroll
    for (int m = 0; m < 8; ++m)
#pragma unroll
      for (int n = 0; n < 4; ++n)
#pragma unroll
        for (int r = 0; r < 4; ++r) {
          int lr = lr0 + m * 16 + lk4 + r;
          int lc = lc0 + n * 16 + lrow;
          __hip_bfloat16 h = __float2bfloat16(acc[m][n][r]);
          SH[lc * 256 + (lr ^ ((lc & 7) << 3))] = *(short*)&h;
        }
    __syncthreads();
    // Coalesced store: Vt[(bq*AA + d)*TT + t0 + lr]; 8-lane groups cover
    // 128B contiguous per d-row per instruction.
    int row0 = mt * 256;
    int bq = row0 >> 11;        // tile never straddles a batch (2048%256==0)
    int t0 = row0 & 2047;
#pragma unroll
    for (int pass = 0; pass < 4; ++pass) {
      int lc = pass * 64 + (tid >> 3);
      int d = ntl * 256 + lc;
      size_t dst = ((size_t)bq * AA + d) * TT + t0;
      int sw = (lc & 7) << 3;
#pragma unroll
      for (int g = 0; g < 4; ++g) {
        int lr = (tid & 7) * 8 + g * 64;
        bf16x8 vv = *(const bf16x8*)&SH[lc * 256 + (lr ^ sw)];
        *(bf16x8*)&Vt[dst + lr] = vv;
      }
    }
  }
}

// ---------------------------------------------------------------------------
// R1-style 128x128 helpers (score + pv bodies) — R5 verbatim.
// ---------------------------------------------------------------------------
__device__ __forceinline__ void stage_tile(const short* __restrict__ g,
                                           size_t stride, short* lds, int tid) {
#pragma unroll
  for (int r = 0; r < 4; ++r) {
    int t = r * 256 + tid;
    int row = t >> 3;
    int c = (t & 7) * 8;
    GLOAD_LDS16(g + (size_t)row * stride + c, lds + (size_t)t * 8);
  }
}

__device__ __forceinline__ void mfma_step(const short* As, const short* Bs,
                                          f32x4 acc[4][4], int lane, int wr,
                                          int wc) {
  int lrow = lane & 15;
  int lk = (lane >> 4) * 8;
#pragma unroll
  for (int kk = 0; kk < 64; kk += 32) {
    bf16x8 a[4], b[4];
#pragma unroll
    for (int i = 0; i < 4; ++i)
      a[i] = *(const bf16x8*)&As[(wr * 64 + i * 16 + lrow) * 64 + kk + lk];
#pragma unroll
    for (int j = 0; j < 4; ++j)
      b[j] = *(const bf16x8*)&Bs[(wc * 64 + j * 16 + lrow) * 64 + kk + lk];
#pragma unroll
    for (int i = 0; i < 4; ++i)
#pragma unroll
      for (int j = 0; j < 4; ++j)
        acc[i][j] =
            __builtin_amdgcn_mfma_f32_16x16x32_bf16(a[i], b[j], acc[i][j], 0, 0, 0);
  }
}

__global__ void cvt_bf16(const float* __restrict__ src, short* __restrict__ dst,
                         int n4) {
  int stride = gridDim.x * blockDim.x;
  for (int i = blockIdx.x * blockDim.x + threadIdx.x; i < n4; i += stride) {
    float4 v = ((const float4*)src)[i];
    __hip_bfloat16 h0 = __float2bfloat16(v.x);
    __hip_bfloat16 h1 = __float2bfloat16(v.y);
    __hip_bfloat16 h2 = __float2bfloat16(v.z);
    __hip_bfloat16 h3 = __float2bfloat16(v.w);
    short4 o;
    o.x = *(short*)&h0;
    o.y = *(short*)&h1;
    o.z = *(short*)&h2;
    o.w = *(short*)&h3;
    ((short4*)dst)[i] = o;
  }
}

// Weights cvt + Ls zeroing (replaces the memset launch).
__global__ void cvt_w3(const float* __restrict__ wq, const float* __restrict__ wk,
                       const float* __restrict__ wv, short* __restrict__ dst,
                       float* __restrict__ Ls) {
  const int n4 = AA * EE / 4;
  int gid = blockIdx.x * blockDim.x + threadIdx.x;
  if (gid < MM) Ls[gid] = 0.f;
  int stride = gridDim.x * blockDim.x;
  for (int i = gid; i < 3 * n4; i += stride) {
    const float* src = (i < n4) ? wq : (i < 2 * n4 ? wk : wv);
    int ii = (i < n4) ? i : (i < 2 * n4 ? i - n4 : i - 2 * n4);
    float4 v = ((const float4*)src)[ii];
    __hip_bfloat16 h0 = __float2bfloat16(v.x);
    __hip_bfloat16 h1 = __float2bfloat16(v.y);
    __hip_bfloat16 h2 = __float2bfloat16(v.z);
    __hip_bfloat16 h3 = __float2bfloat16(v.w);
    short4 o;
    o.x = *(short*)&h0;
    o.y = *(short*)&h1;
    o.z = *(short*)&h2;
    o.w = *(short*)&h3;
    ((short4*)dst)[i] = o;
  }
}

// ---------------------------------------------------------------------------
// Scores: compact lower-triangle grid 1088 (8 b x 136 tri), XCD = batch.
// ---------------------------------------------------------------------------
__global__ __launch_bounds__(256) void score_gemm(const short* __restrict__ Qb,
                                                  const short* __restrict__ Kb,
                                                  short* __restrict__ Pu,
                                                  float* __restrict__ lsum) {
  int f = blockIdx.x;
  int b = f & 7;
  int j = f >> 3;  // tri index in [0,136)
  int mt = 0;
  while ((mt + 1) * (mt + 2) / 2 <= j) ++mt;
  int nt = j - mt * (mt + 1) / 2;
  int q0 = mt * 128, c0 = nt * 128;

  __shared__ __align__(16) short As[128 * 64];
  __shared__ __align__(16) short Bs[128 * 64];
  int tid = threadIdx.x;
  int lane = tid & 63, wid = tid >> 6, wr = wid >> 1, wc = wid & 1;
  const short* Q = Qb + (size_t)b * TT * AA;
  const short* K = Kb + (size_t)b * TT * AA;
  f32x4 acc[4][4];
#pragma unroll
  for (int i = 0; i < 4; ++i)
#pragma unroll
    for (int jj = 0; jj < 4; ++jj) acc[i][jj] = (f32x4){0.f, 0.f, 0.f, 0.f};

  for (int k0 = 0; k0 < AA; k0 += 64) {
    stage_tile(Q + (size_t)q0 * AA + k0, AA, As, tid);
    stage_tile(K + (size_t)c0 * AA + k0, AA, Bs, tid);
    __syncthreads();
    mfma_step(As, Bs, acc, lane, wr, wc);
    __syncthreads();
  }
  const float scale = 0.03125f;  // 1/sqrt(1024)
  short* P = Pu + (size_t)b * TT * TT;
  int lrow = lane & 15, lk4 = (lane >> 4) * 4;
#pragma unroll
  for (int i = 0; i < 4; ++i) {
#pragma unroll
    for (int r = 0; r < 4; ++r) {
      int q = q0 + wr * 64 + i * 16 + lk4 + r;
      float rs = 0.f;
#pragma unroll
      for (int jj = 0; jj < 4; ++jj) {
        int kx = c0 + wc * 64 + jj * 16 + lrow;
        float e = (kx <= q) ? __expf(acc[i][jj][r] * scale) : 0.f;
        rs += e;
        __hip_bfloat16 h = __float2bfloat16(e);
        P[(size_t)q * TT + kx] = *(short*)&h;
      }
      rs += __shfl_xor(rs, 1);
      rs += __shfl_xor(rs, 2);
      rs += __shfl_xor(rs, 4);
      rs += __shfl_xor(rs, 8);
      if (lrow == 0) atomicAdd(&lsum[b * TT + q], rs);
    }
  }
}

// ---------------------------------------------------------------------------
// PV balanced pairing: block handles q-strips mt=p and 15-p. grid 512.
// ---------------------------------------------------------------------------
__global__ __launch_bounds__(256) void pv_gemm(const short* __restrict__ Pu,
                                               const short* __restrict__ Vt,
                                               const float* __restrict__ lsum,
                                               float* __restrict__ out) {
  int f = blockIdx.x;
  int b = f & 7;
  int j = f >> 3;          // [0,64)
  int p = j >> 3;          // [0,8)
  int nt = j & 7;
  int n0 = nt * 128;

  __shared__ __align__(16) short As[128 * 64];
  __shared__ __align__(16) short Bs[128 * 64];
  int tid = threadIdx.x;
  int lane = tid & 63, wid = tid >> 6, wr = wid >> 1, wc = wid & 1;
  const short* P = Pu + (size_t)b * TT * TT;
  const short* V = Vt + (size_t)b * AA * TT;
  int lrow = lane & 15, lk4 = (lane >> 4) * 4;

#pragma unroll
  for (int s = 0; s < 2; ++s) {
    int mt = s ? (15 - p) : p;
    int q0 = mt * 128;
    f32x4 acc[4][4];
#pragma unroll
    for (int i = 0; i < 4; ++i)
#pragma unroll
      for (int jj = 0; jj < 4; ++jj) acc[i][jj] = (f32x4){0.f, 0.f, 0.f, 0.f};

    int kend = q0 + 128;
    for (int k0 = 0; k0 < kend; k0 += 64) {
      stage_tile(P + (size_t)q0 * TT + k0, TT, As, tid);
      stage_tile(V + (size_t)n0 * TT + k0, TT, Bs, tid);
      __syncthreads();
      mfma_step(As, Bs, acc, lane, wr, wc);
      __syncthreads();
    }
#pragma unroll
    for (int i = 0; i < 4; ++i) {
#pragma unroll
      for (int r = 0; r < 4; ++r) {
        int q = q0 + wr * 64 + i * 16 + lk4 + r;
        float linv = 1.0f / lsum[b * TT + q];
#pragma unroll
        for (int jj = 0; jj < 4; ++jj) {
          int d = n0 + wc * 64 + jj * 16 + lrow;
          out[((size_t)(b * TT + q)) * AA + d] = acc[i][jj][r] * linv;
        }
      }
    }
  }
}

extern "C" void kernel_launch(void* const* d_in, const int* in_sizes, int n_in,
                              void* d_out, int out_size, void* d_ws,
                              size_t ws_size, hipStream_t stream) {
  const float* x = (const float*)d_in[0];
  const float* Wq = (const float*)d_in[1];
  const float* Wk = (const float*)d_in[2];
  const float* Wv = (const float*)d_in[3];

  char* ws = (char*)d_ws;
  size_t oWb = 0;
  size_t oQb = oWb + (size_t)3 * AA * EE * 2;   // 6 MB weights
  size_t oKb = oQb + (size_t)MM * AA * 2;
  size_t oVt = oKb + (size_t)MM * AA * 2;       // Vb eliminated
  size_t oLs = oVt + (size_t)MM * AA * 2;
  size_t oXb = oLs + (size_t)MM * 4;
  size_t oPu = oXb;  // Pu (67MB) overlaps Xb (33MB): Xb dead after qkv

  short* Wb = (short*)(ws + oWb);
  short* Qb = (short*)(ws + oQb);
  short* Kb = (short*)(ws + oKb);
  short* Vt = (short*)(ws + oVt);
  float* Ls = (float*)(ws + oLs);
  short* Xb = (short*)(ws + oXb);
  short* Pu = (short*)(ws + oPu);

  cvt_bf16<<<2048, 256, 0, stream>>>(x, Xb, MM * EE / 4);
  cvt_w3<<<768, 256, 0, stream>>>(Wq, Wk, Wv, Wb, Ls);

  qkv_gemm8<<<768, 512, 0, stream>>>(Xb, Wb, Qb, Vt);
  score_gemm<<<1088, 256, 0, stream>>>(Qb, Kb, Pu, Ls);
  pv_gemm<<<512, 256, 0, stream>>>(Pu, Vt, Ls, (float*)d_out);
}

// Round 9
// 260.827 us; speedup vs baseline: 3.9005x; 1.0187x over previous
//
#include <hip/hip_runtime.h>
#include <hip/hip_bf16.h>
#include <stdint.h>

// SingleHeadAttention: B=8 T=2048 E=1024 A=1024, fp32 in/out, bf16 MFMA inside.
// Round 9 = R8 (265.7us) with two changes:
//   1) gemm256_core staging stream made template-faithful: uniform 1 region
//      (2 gload_lds) per phase -- B-k1(t+1)@ph0, B-k0(t+2)@ph1, A-k0(t+2)@ph2,
//      A-k1(t+2)@ph3 -- boundary vmcnt(6) (tile t+1 forced complete, 3 regions
//      in flight). Prologue: tile0 full + tile1 minus B1, vmcnt(6).
//   2) cvt_bf16 + cvt_w3 + Ls-zero merged into one `prep` kernel.
// Everything else (qkv fused V-transpose epilogue, score, pv) = R8 verbatim.

#define BB 8
#define TT 2048
#define EE 1024
#define AA 1024
#define MM (BB * TT)  // 16384

typedef short bf16x8 __attribute__((ext_vector_type(8)));
typedef float f32x4 __attribute__((ext_vector_type(4)));

#define GLOAD_LDS16(g, l)                                                      \
  __builtin_amdgcn_global_load_lds(                                            \
      (const __attribute__((address_space(1))) void*)(g),                      \
      (__attribute__((address_space(3))) void*)(l), 16, 0, 0)

#define SBAR()                               \
  do {                                       \
    __builtin_amdgcn_sched_barrier(0);       \
    __builtin_amdgcn_s_barrier();            \
    __builtin_amdgcn_sched_barrier(0);       \
  } while (0)

#define LGKM0()                                          \
  do {                                                   \
    asm volatile("s_waitcnt lgkmcnt(0)" ::: "memory");   \
    __builtin_amdgcn_sched_barrier(0);                   \
  } while (0)

#define VMCNT(n)                                              \
  do {                                                        \
    asm volatile("s_waitcnt vmcnt(" #n ")" ::: "memory");     \
    __builtin_amdgcn_sched_barrier(0);                        \
  } while (0)

// ---------------------------------------------------------------------------
// 256x256x(K) bt-GEMM core. 512 thr = 8 waves (2M x 4N), BK=64.
// LDS/operand: [2 buf][2 ksub][256 row][32 kc] shorts, st_16x32 swizzle.
// Staging: gload_lds w16, linear dest, pre-swizzled source. Uniform stream:
// one 16KB region per phase, boundary vmcnt(6).
// Hazards: each region staged >=1 closing-barrier after its last reader's
// lgkm (B-k0: read ph0 -> staged ph1; A-k0: ph0/ph1 -> ph2; A-k1: ph1/ph2 ->
// ph3; B-k1(t+1) overwrites B-k1(t-1): read ph2(t-1) -> staged ph0(t)).
// ---------------------------------------------------------------------------
__device__ __forceinline__ void gemm256_core(
    const short* __restrict__ gA, int lda, int a0row,
    const short* __restrict__ gB, int ldb, int b0row, int NT, short* As,
    short* Bs, f32x4 (*acc)[4]) {
  const int tid = threadIdx.x;
  const int lane = tid & 63;
  const int w = tid >> 6;
  const int wr = w >> 2, wc = w & 3;
  const int lrow = lane & 15;
  const int lk8 = (lane >> 4) * 8;
  const int swz = ((lrow >> 3) & 1) << 4;
  const int baseA = (((wr * 128 + lrow) * 32) + lk8) ^ swz;
  const int baseB = (((wc * 64 + lrow) * 32) + lk8) ^ swz;

  const short* pA[2];
  const short* pB[2];
  int dL[2];
#pragma unroll
  for (int i = 0; i < 2; ++i) {
    int chunk = 2 * w + i;
    int P = chunk * 1024 + lane * 16;           // phys byte in 16KB region
    int L = P ^ (((P >> 9) & 1) << 5);          // logical byte
    int row = L >> 6;
    int kb2 = (L & 63) >> 1;                    // shorts
    pA[i] = gA + (size_t)(a0row + row) * lda + kb2;
    pB[i] = gB + (size_t)(b0row + row) * ldb + kb2;
    dL[i] = chunk * 512 + lane * 8;
  }

#define STG_A(tl, s)                                                           \
  do {                                                                         \
    int _o = (tl) * 64 + (s) * 32;                                             \
    short* _d = As + (((tl) & 1) << 14) + ((s) << 13);                         \
    GLOAD_LDS16(pA[0] + _o, _d + dL[0]);                                       \
    GLOAD_LDS16(pA[1] + _o, _d + dL[1]);                                       \
  } while (0)
#define STG_B(tl, s)                                                           \
  do {                                                                         \
    int _o = (tl) * 64 + (s) * 32;                                             \
    short* _d = Bs + (((tl) & 1) << 14) + ((s) << 13);                         \
    GLOAD_LDS16(pB[0] + _o, _d + dL[0]);                                       \
    GLOAD_LDS16(pB[1] + _o, _d + dL[1]);                                       \
  } while (0)

  // Prologue: tile0 full [B0 A0 B1 A1]; tile1 minus B1 (ph0 of t=0 stages it).
  STG_B(0, 0); STG_A(0, 0); STG_B(0, 1); STG_A(0, 1);
  if (NT > 1) {
    STG_B(1, 0); STG_A(1, 0); STG_A(1, 1);
    VMCNT(6);  // 14 issued; tile0's 8 complete, tile1's 3 regions in flight
  } else {
    VMCNT(0);
  }
  SBAR();

  for (int t = 0; t < NT; ++t) {
    short* Ac = As + (t & 1) * 16384;
    short* Bc = Bs + (t & 1) * 16384;
    const bool stg = (t < NT - 2);
    bf16x8 a0[4], a1[4], a2[4], a3[4], b0[4], b1[4];

    // ---- phase 0: read A m0-3/kk0 + B kk0; stage B-k1(t+1); MFMA (mh0,kk0)
#pragma unroll
    for (int m = 0; m < 4; ++m) a0[m] = *(const bf16x8*)&Ac[baseA + m * 512];
#pragma unroll
    for (int n = 0; n < 4; ++n) b0[n] = *(const bf16x8*)&Bc[baseB + n * 512];
    if (t < NT - 1) STG_B(t + 1, 1);
    SBAR();
    LGKM0();
    __builtin_amdgcn_s_setprio(1);
#pragma unroll
    for (int m = 0; m < 4; ++m)
#pragma unroll
      for (int n = 0; n < 4; ++n)
        acc[m][n] = __builtin_amdgcn_mfma_f32_16x16x32_bf16(a0[m], b0[n],
                                                            acc[m][n], 0, 0, 0);
    __builtin_amdgcn_s_setprio(0);
    SBAR();

    // ---- phase 1: read A m4-7/kk0 + A m0-3/kk1; stage B-k0(t+2); MFMA
#pragma unroll
    for (int m = 0; m < 4; ++m)
      a1[m] = *(const bf16x8*)&Ac[baseA + (m + 4) * 512];
#pragma unroll
    for (int m = 0; m < 4; ++m)
      a2[m] = *(const bf16x8*)&Ac[8192 + baseA + m * 512];
    if (stg) STG_B(t + 2, 0);
    SBAR();
    LGKM0();
    __builtin_amdgcn_s_setprio(1);
#pragma unroll
    for (int m = 0; m < 4; ++m)
#pragma unroll
      for (int n = 0; n < 4; ++n)
        acc[m + 4][n] = __builtin_amdgcn_mfma_f32_16x16x32_bf16(
            a1[m], b0[n], acc[m + 4][n], 0, 0, 0);
    __builtin_amdgcn_s_setprio(0);
    SBAR();

    // ---- phase 2: read A m4-7/kk1 + B kk1; stage A-k0(t+2); MFMA
#pragma unroll
    for (int m = 0; m < 4; ++m)
      a3[m] = *(const bf16x8*)&Ac[8192 + baseA + (m + 4) * 512];
#pragma unroll
    for (int n = 0; n < 4; ++n)
      b1[n] = *(const bf16x8*)&Bc[8192 + baseB + n * 512];
    if (stg) STG_A(t + 2, 0);
    SBAR();
    LGKM0();
    __builtin_amdgcn_s_setprio(1);
#pragma unroll
    for (int m = 0; m < 4; ++m)
#pragma unroll
      for (int n = 0; n < 4; ++n)
        acc[m][n] = __builtin_amdgcn_mfma_f32_16x16x32_bf16(a2[m], b1[n],
                                                            acc[m][n], 0, 0, 0);
    __builtin_amdgcn_s_setprio(0);
    SBAR();

    // ---- phase 3: stage A-k1(t+2); boundary vmcnt(6); MFMA (mh1,kk1)
    if (stg) {
      STG_A(t + 2, 1);
      VMCNT(6);  // newest 6 = B0,A0,A1 of t+2; B-k1(t+1) & older forced done
    } else if (t == NT - 2) {
      VMCNT(0);  // tail: drain tile NT-1 (incl. B-k1 staged @ph0 this tile)
    }
    SBAR();
    __builtin_amdgcn_s_setprio(1);
#pragma unroll
    for (int m = 0; m < 4; ++m)
#pragma unroll
      for (int n = 0; n < 4; ++n)
        acc[m + 4][n] = __builtin_amdgcn_mfma_f32_16x16x32_bf16(
            a3[m], b1[n], acc[m + 4][n], 0, 0, 0);
    __builtin_amdgcn_s_setprio(0);
    SBAR();
  }
#undef STG_A
#undef STG_B
}

// ---------------------------------------------------------------------------
// Fused QKV: grid 768 x 512thr, XCD-chunked. z<2 -> row-major Q/K store.
// z==2 -> transpose V through the (dead) 128KB LDS and store Vt[b][d][t].
// ---------------------------------------------------------------------------
__global__ __launch_bounds__(512, 2) void qkv_gemm8(
    const short* __restrict__ xb, const short* __restrict__ Wb,
    short* __restrict__ qk, short* __restrict__ Vt) {
  __shared__ __align__(16) short SH[65536];  // 128 KiB: As | Bs
  short* As = SH;
  short* Bs = SH + 32768;
  int f = blockIdx.x;
  int s = (f & 7) * 96 + (f >> 3);  // XCD-chunked (768 % 8 == 0)
  int mt = s / 12, nt = s % 12;
  int z = nt >> 2, ntl = nt & 3;
  const short* gB = Wb + (size_t)z * AA * EE + (size_t)(ntl * 256) * EE;
  f32x4 acc[8][4];
#pragma unroll
  for (int m = 0; m < 8; ++m)
#pragma unroll
    for (int n = 0; n < 4; ++n) acc[m][n] = (f32x4){0.f, 0.f, 0.f, 0.f};
  gemm256_core(xb, EE, mt * 256, gB, EE, 0, EE / 64, As, Bs, acc);

  int tid = threadIdx.x;
  int lane = tid & 63, w = tid >> 6, wr = w >> 2, wc = w & 3;
  int lrow = lane & 15, lk4 = (lane >> 4) * 4;

  if (z < 2) {
    short* o = qk + (size_t)z * MM * AA;
    int row0 = mt * 256 + wr * 128;
    int col0 = ntl * 256 + wc * 64;
#pragma unroll
    for (int m = 0; m < 8; ++m)
#pragma unroll
      for (int n = 0; n < 4; ++n)
#pragma unroll
        for (int r = 0; r < 4; ++r) {
          int row = row0 + m * 16 + lk4 + r;
          int col = col0 + n * 16 + lrow;
          __hip_bfloat16 h = __float2bfloat16(acc[m][n][r]);
          o[(size_t)row * AA + col] = *(short*)&h;
        }
  } else {
    // V tile: stage transposed into SH[lc][lr] bf16 with 8-short-granule XOR
    // swizzle (b128-readable), then coalesced Vt stores.
    __syncthreads();
    int lr0 = wr * 128, lc0 = wc * 64;
#pragma unroll
    for (int m = 0; m < 8; ++m)
#pragma unroll
      for (int n = 0; n < 4; ++n)
#pragma unroll
        for (int r = 0; r < 4; ++r) {
          int lr = lr0 + m * 16 + lk4 + r;
          int lc = lc0 + n * 16 + lrow;
          __hip_bfloat16 h = __float2bfloat16(acc[m][n][r]);
          SH[lc * 256 + (lr ^ ((lc & 7) << 3))] = *(short*)&h;
        }
    __syncthreads();
    int row0 = mt * 256;
    int bq = row0 >> 11;        // tile never straddles a batch (2048%256==0)
    int t0 = row0 & 2047;
#pragma unroll
    for (int pass = 0; pass < 4; ++pass) {
      int lc = pass * 64 + (tid >> 3);
      int d = ntl * 256 + lc;
      size_t dst = ((size_t)bq * AA + d) * TT + t0;
      int sw = (lc & 7) << 3;
#pragma unroll
      for (int g = 0; g < 4; ++g) {
        int lr = (tid & 7) * 8 + g * 64;
        bf16x8 vv = *(const bf16x8*)&SH[lc * 256 + (lr ^ sw)];
        *(bf16x8*)&Vt[dst + lr] = vv;
      }
    }
  }
}

// ---------------------------------------------------------------------------
// R1-style 128x128 helpers (score + pv bodies).
// ---------------------------------------------------------------------------
__device__ __forceinline__ void stage_tile(const short* __restrict__ g,
                                           size_t stride, short* lds, int tid) {
#pragma unroll
  for (int r = 0; r < 4; ++r) {
    int t = r * 256 + tid;
    int row = t >> 3;
    int c = (t & 7) * 8;
    GLOAD_LDS16(g + (size_t)row * stride + c, lds + (size_t)t * 8);
  }
}

__device__ __forceinline__ void mfma_step(const short* As, const short* Bs,
                                          f32x4 acc[4][4], int lane, int wr,
                                          int wc) {
  int lrow = lane & 15;
  int lk = (lane >> 4) * 8;
#pragma unroll
  for (int kk = 0; kk < 64; kk += 32) {
    bf16x8 a[4], b[4];
#pragma unroll
    for (int i = 0; i < 4; ++i)
      a[i] = *(const bf16x8*)&As[(wr * 64 + i * 16 + lrow) * 64 + kk + lk];
#pragma unroll
    for (int j = 0; j < 4; ++j)
      b[j] = *(const bf16x8*)&Bs[(wc * 64 + j * 16 + lrow) * 64 + kk + lk];
#pragma unroll
    for (int i = 0; i < 4; ++i)
#pragma unroll
      for (int j = 0; j < 4; ++j)
        acc[i][j] =
            __builtin_amdgcn_mfma_f32_16x16x32_bf16(a[i], b[j], acc[i][j], 0, 0, 0);
  }
}

// ---------------------------------------------------------------------------
// prep: X -> bf16, [Wq|Wk|Wv] -> bf16, Ls = 0. One launch.
// ---------------------------------------------------------------------------
__global__ void prep(const float* __restrict__ x, const float* __restrict__ wq,
                     const float* __restrict__ wk, const float* __restrict__ wv,
                     short* __restrict__ Xb, short* __restrict__ Wb,
                     float* __restrict__ Ls) {
  const int nx4 = MM * EE / 4;
  const int nw4 = AA * EE / 4;
  int gid = blockIdx.x * blockDim.x + threadIdx.x;
  if (gid < MM) Ls[gid] = 0.f;
  int stride = gridDim.x * blockDim.x;
  for (int i = gid; i < nx4 + 3 * nw4; i += stride) {
    const float* src;
    short* dst;
    int ii;
    if (i < nx4) {
      src = x; dst = Xb; ii = i;
    } else {
      int j = i - nx4;
      int z = j / nw4;
      ii = j - z * nw4;
      src = (z == 0) ? wq : (z == 1 ? wk : wv);
      dst = Wb + (size_t)z * AA * EE;
    }
    float4 v = ((const float4*)src)[ii];
    __hip_bfloat16 h0 = __float2bfloat16(v.x);
    __hip_bfloat16 h1 = __float2bfloat16(v.y);
    __hip_bfloat16 h2 = __float2bfloat16(v.z);
    __hip_bfloat16 h3 = __float2bfloat16(v.w);
    short4 o;
    o.x = *(short*)&h0;
    o.y = *(short*)&h1;
    o.z = *(short*)&h2;
    o.w = *(short*)&h3;
    ((short4*)dst)[ii] = o;
  }
}

// ---------------------------------------------------------------------------
// Scores: compact lower-triangle grid 1088 (8 b x 136 tri), XCD = batch.
// ---------------------------------------------------------------------------
__global__ __launch_bounds__(256) void score_gemm(const short* __restrict__ Qb,
                                                  const short* __restrict__ Kb,
                                                  short* __restrict__ Pu,
                                                  float* __restrict__ lsum) {
  int f = blockIdx.x;
  int b = f & 7;
  int j = f >> 3;  // tri index in [0,136)
  int mt = 0;
  while ((mt + 1) * (mt + 2) / 2 <= j) ++mt;
  int nt = j - mt * (mt + 1) / 2;
  int q0 = mt * 128, c0 = nt * 128;

  __shared__ __align__(16) short As[128 * 64];
  __shared__ __align__(16) short Bs[128 * 64];
  int tid = threadIdx.x;
  int lane = tid & 63, wid = tid >> 6, wr = wid >> 1, wc = wid & 1;
  const short* Q = Qb + (size_t)b * TT * AA;
  const short* K = Kb + (size_t)b * TT * AA;
  f32x4 acc[4][4];
#pragma unroll
  for (int i = 0; i < 4; ++i)
#pragma unroll
    for (int jj = 0; jj < 4; ++jj) acc[i][jj] = (f32x4){0.f, 0.f, 0.f, 0.f};

  for (int k0 = 0; k0 < AA; k0 += 64) {
    stage_tile(Q + (size_t)q0 * AA + k0, AA, As, tid);
    stage_tile(K + (size_t)c0 * AA + k0, AA, Bs, tid);
    __syncthreads();
    mfma_step(As, Bs, acc, lane, wr, wc);
    __syncthreads();
  }
  const float scale = 0.03125f;  // 1/sqrt(1024)
  short* P = Pu + (size_t)b * TT * TT;
  int lrow = lane & 15, lk4 = (lane >> 4) * 4;
#pragma unroll
  for (int i = 0; i < 4; ++i) {
#pragma unroll
    for (int r = 0; r < 4; ++r) {
      int q = q0 + wr * 64 + i * 16 + lk4 + r;
      float rs = 0.f;
#pragma unroll
      for (int jj = 0; jj < 4; ++jj) {
        int kx = c0 + wc * 64 + jj * 16 + lrow;
        float e = (kx <= q) ? __expf(acc[i][jj][r] * scale) : 0.f;
        rs += e;
        __hip_bfloat16 h = __float2bfloat16(e);
        P[(size_t)q * TT + kx] = *(short*)&h;
      }
      rs += __shfl_xor(rs, 1);
      rs += __shfl_xor(rs, 2);
      rs += __shfl_xor(rs, 4);
      rs += __shfl_xor(rs, 8);
      if (lrow == 0) atomicAdd(&lsum[b * TT + q], rs);
    }
  }
}

// ---------------------------------------------------------------------------
// PV balanced pairing: block handles q-strips mt=p and 15-p. grid 512.
// ---------------------------------------------------------------------------
__global__ __launch_bounds__(256) void pv_gemm(const short* __restrict__ Pu,
                                               const short* __restrict__ Vt,
                                               const float* __restrict__ lsum,
                                               float* __restrict__ out) {
  int f = blockIdx.x;
  int b = f & 7;
  int j = f >> 3;          // [0,64)
  int p = j >> 3;          // [0,8)
  int nt = j & 7;
  int n0 = nt * 128;

  __shared__ __align__(16) short As[128 * 64];
  __shared__ __align__(16) short Bs[128 * 64];
  int tid = threadIdx.x;
  int lane = tid & 63, wid = tid >> 6, wr = wid >> 1, wc = wid & 1;
  const short* P = Pu + (size_t)b * TT * TT;
  const short* V = Vt + (size_t)b * AA * TT;
  int lrow = lane & 15, lk4 = (lane >> 4) * 4;

#pragma unroll
  for (int s = 0; s < 2; ++s) {
    int mt = s ? (15 - p) : p;
    int q0 = mt * 128;
    f32x4 acc[4][4];
#pragma unroll
    for (int i = 0; i < 4; ++i)
#pragma unroll
      for (int jj = 0; jj < 4; ++jj) acc[i][jj] = (f32x4){0.f, 0.f, 0.f, 0.f};

    int kend = q0 + 128;
    for (int k0 = 0; k0 < kend; k0 += 64) {
      stage_tile(P + (size_t)q0 * TT + k0, TT, As, tid);
      stage_tile(V + (size_t)n0 * TT + k0, TT, Bs, tid);
      __syncthreads();
      mfma_step(As, Bs, acc, lane, wr, wc);
      __syncthreads();
    }
#pragma unroll
    for (int i = 0; i < 4; ++i) {
#pragma unroll
      for (int r = 0; r < 4; ++r) {
        int q = q0 + wr * 64 + i * 16 + lk4 + r;
        float linv = 1.0f / lsum[b * TT + q];
#pragma unroll
        for (int jj = 0; jj < 4; ++jj) {
          int d = n0 + wc * 64 + jj * 16 + lrow;
          out[((size_t)(b * TT + q)) * AA + d] = acc[i][jj][r] * linv;
        }
      }
    }
  }
}

extern "C" void kernel_launch(void* const* d_in, const int* in_sizes, int n_in,
                              void* d_out, int out_size, void* d_ws,
                              size_t ws_size, hipStream_t stream) {
  const float* x = (const float*)d_in[0];
  const float* Wq = (const float*)d_in[1];
  const float* Wk = (const float*)d_in[2];
  const float* Wv = (const float*)d_in[3];

  char* ws = (char*)d_ws;
  size_t oWb = 0;
  size_t oQb = oWb + (size_t)3 * AA * EE * 2;   // 6 MB weights
  size_t oKb = oQb + (size_t)MM * AA * 2;
  size_t oVt = oKb + (size_t)MM * AA * 2;       // Vb eliminated
  size_t oLs = oVt + (size_t)MM * AA * 2;
  size_t oXb = oLs + (size_t)MM * 4;
  size_t oPu = oXb;  // Pu (67MB) overlaps Xb (33MB): Xb dead after qkv

  short* Wb = (short*)(ws + oWb);
  short* Qb = (short*)(ws + oQb);
  short* Kb = (short*)(ws + oKb);
  short* Vt = (short*)(ws + oVt);
  float* Ls = (float*)(ws + oLs);
  short* Xb = (short*)(ws + oXb);
  short* Pu = (short*)(ws + oPu);

  prep<<<2048, 256, 0, stream>>>(x, Wq, Wk, Wv, Xb, Wb, Ls);

  qkv_gemm8<<<768, 512, 0, stream>>>(Xb, Wb, Qb, Vt);
  score_gemm<<<1088, 256, 0, stream>>>(Qb, Kb, Pu, Ls);
  pv_gemm<<<512, 256, 0, stream>>>(Pu, Vt, Ls, (float*)d_out);
}